// Round 1
// baseline (894.396 us; speedup 1.0000x reference)
//
#include <hip/hip_runtime.h>
#include <math.h>

#define KTOP 5

// Tree argmax over the low WIDTH lanes of the wave (result broadcast to all 64).
// Tie-break: smaller index wins (matches jax.lax.top_k).
template <int WIDTH>
__device__ __forceinline__ void wave_argmax(float& v, int& i) {
#pragma unroll
    for (int off = WIDTH / 2; off > 0; off >>= 1) {
        float ov = __shfl_down(v, off);
        int   oi = __shfl_down(i, off);
        bool take = (ov > v) || (ov == v && oi < i);
        v = take ? ov : v;
        i = take ? oi : i;
    }
    v = __shfl(v, 0);
    i = __shfl(i, 0);
}

// Each lane owns 8 consecutive output columns: col = lane*8.
// Sum the 5 selected table rows and store 2x float4 (coalesced 2KB/wave).
__device__ __forceinline__ void gather_store(const float* __restrict__ table,
                                             const int* sel,
                                             float* __restrict__ outrow,
                                             int lane) {
    const int col = lane * 8;
    float acc[8] = {0.f, 0.f, 0.f, 0.f, 0.f, 0.f, 0.f, 0.f};
#pragma unroll
    for (int k = 0; k < KTOP; ++k) {
        const float4* t = reinterpret_cast<const float4*>(table + (size_t)sel[k] * 512 + col);
        float4 a = t[0];
        float4 b = t[1];
        acc[0] += a.x; acc[1] += a.y; acc[2] += a.z; acc[3] += a.w;
        acc[4] += b.x; acc[5] += b.y; acc[6] += b.z; acc[7] += b.w;
    }
    float4* o = reinterpret_cast<float4*>(outrow + col);
    o[0] = make_float4(acc[0], acc[1], acc[2], acc[3]);
    o[1] = make_float4(acc[4], acc[5], acc[6], acc[7]);
}

__global__ __launch_bounds__(256) void select_topk_kernel(
    const float* __restrict__ node_w,   // [N,160]
    const float* __restrict__ edge_w,   // [E,27]
    const float* __restrict__ knode_t,  // [160,512]
    const float* __restrict__ kedge_t,  // [27,512]
    float* __restrict__ out_node,       // [N,512]
    float* __restrict__ out_edge,       // [E,512]
    int N, int E, int node_blocks) {
    const int wave = threadIdx.x >> 6;
    const int lane = threadIdx.x & 63;

    if ((int)blockIdx.x < node_blocks) {
        // ---- node rows: 160 candidate classes per row ----
        const int row = blockIdx.x * 4 + wave;
        if (row >= N) return;
        const float* w = node_w + (size_t)row * 160;
        float v0 = w[lane];
        float v1 = w[64 + lane];
        float v2 = (lane < 32) ? w[128 + lane] : -INFINITY;
        int sel[KTOP];
#pragma unroll
        for (int k = 0; k < KTOP; ++k) {
            // local argmax over the up-to-3 values this lane owns
            // (strict > keeps smaller-index preference)
            float lv = v0; int li = lane;
            if (v1 > lv) { lv = v1; li = lane + 64; }
            if (v2 > lv) { lv = v2; li = lane + 128; }
            wave_argmax<64>(lv, li);
            sel[k] = li;
            if (li == lane)            v0 = -INFINITY;
            else if (li == lane + 64)  v1 = -INFINITY;
            else if (li == lane + 128) v2 = -INFINITY;
        }
        gather_store(knode_t, sel, out_node + (size_t)row * 512, lane);
    } else {
        // ---- edge rows: 27 candidate classes per row ----
        const int row = ((int)blockIdx.x - node_blocks) * 4 + wave;
        if (row >= E) return;
        const float* w = edge_w + (size_t)row * 27;
        float v = (lane < 27) ? w[lane] : -INFINITY;
        int sel[KTOP];
#pragma unroll
        for (int k = 0; k < KTOP; ++k) {
            float lv = v; int li = lane;
            // only lanes 0..31 hold candidates; 5-step tree suffices
            wave_argmax<32>(lv, li);
            sel[k] = li;
            if (li == lane) v = -INFINITY;
        }
        gather_store(kedge_t, sel, out_edge + (size_t)row * 512, lane);
    }
}

extern "C" void kernel_launch(void* const* d_in, const int* in_sizes, int n_in,
                              void* d_out, int out_size, void* d_ws, size_t ws_size,
                              hipStream_t stream) {
    const float* node_w  = (const float*)d_in[0];
    const float* edge_w  = (const float*)d_in[1];
    const float* knode_t = (const float*)d_in[2];
    const float* kedge_t = (const float*)d_in[3];

    const int N = in_sizes[0] / 160;  // 600
    const int E = in_sizes[1] / 27;   // 359400

    float* out      = (float*)d_out;
    float* out_node = out;
    float* out_edge = out + (size_t)N * 512;

    const int node_blocks = (N + 3) / 4;  // 4 rows (waves) per 256-thread block
    const int edge_blocks = (E + 3) / 4;

    dim3 grid(node_blocks + edge_blocks);
    dim3 block(256);
    hipLaunchKernelGGL(select_topk_kernel, grid, block, 0, stream,
                       node_w, edge_w, knode_t, kedge_t,
                       out_node, out_edge, N, E, node_blocks);
}